// Round 4
// baseline (1712.063 us; speedup 1.0000x reference)
//
#include <hip/hip_runtime.h>
#include <math.h>

#define Bsz  1024
#define Tlen 128
#define Hdim 512
#define NCLS 10
#define NDIG 3
#define G4   2048   // 4*H

typedef short s8v __attribute__((ext_vector_type(8)));    // 8 bf16 (4 VGPRs)
typedef float f16v __attribute__((ext_vector_type(16)));  // 32x32 mfma acc

// ---- workspace layout (bytes) ----
// W6 : 2 MB  bf16 frag chunks: uint4 idx = (wn*32+ks)*64 + lane, wn=0..63
//      elem j of lane l: n = wn*32+(l&31) -> jp=n>>2,g=n&3, row=g*512+jp,
//      k = ks*16 + (l>>5)*8 + j
// gxd: 24 KB fp32 [d][jp*4+g]  (pad to 32 KB)
// h0/h1: 1 MB bf16 each, chunk layout per mt: uint4 idx = mt*2048 + ks*64 + l
//      elem j = h[b = mt*32 + (l&31)][jp = ks*16 + (l>>5)*8 + j]
// cnt: 4 KB (32 counters, stride 32 ints)
#define W6_OFF  0
#define GXD_OFF (2*1024*1024)
#define H0_OFF  (GXD_OFF + 32*1024)
#define H1_OFF  (H0_OFF + 1024*1024)
#define CNT_OFF (H1_OFF + 1024*1024)

static __device__ __forceinline__ unsigned short f2bf(float f) {
    unsigned int u = __float_as_uint(f);
    u = (u + 0x7FFFu + ((u >> 16) & 1u)) >> 16;   // RNE
    return (unsigned short)u;
}
static __device__ __forceinline__ float bf2f(unsigned short s) {
    return __uint_as_float(((unsigned int)s) << 16);
}
static __device__ __forceinline__ s8v u2s(uint4 v) {
    union { uint4 u; s8v s; } x; x.u = v; return x.s;
}

// ---- prep: W6 fragment chunks for register-resident B ----
__global__ __launch_bounds__(256) void prep_w6(const float* __restrict__ Wh,
                                               unsigned short* __restrict__ W6) {
    int idx = blockIdx.x * 256 + threadIdx.x;   // 0..131071
    int l  = idx & 63;
    int c  = idx >> 6;          // wn*32 + ks
    int ks = c & 31, wn = c >> 5;
    int n  = wn * 32 + (l & 31);
    int jp = n >> 2, g = n & 3;
    int row = g * Hdim + jp;
    int kb  = ks * 16 + (l >> 5) * 8;
    const float* src = &Wh[(size_t)row * Hdim + kb];
    unsigned int p0 = f2bf(src[0]) | ((unsigned int)f2bf(src[1]) << 16);
    unsigned int p1 = f2bf(src[2]) | ((unsigned int)f2bf(src[3]) << 16);
    unsigned int p2 = f2bf(src[4]) | ((unsigned int)f2bf(src[5]) << 16);
    unsigned int p3 = f2bf(src[6]) | ((unsigned int)f2bf(src[7]) << 16);
    ((uint4*)W6)[idx] = make_uint4(p0, p1, p2, p3);
}

__global__ __launch_bounds__(256) void prep_gxd(const float* __restrict__ emb,
                                                const float* __restrict__ Wx,
                                                const float* __restrict__ b,
                                                float* __restrict__ gxd) {
    int idx = blockIdx.x * 256 + threadIdx.x;
    if (idx >= NDIG * G4) return;
    int col = idx % G4;
    int d   = idx / G4;
    int jp  = col >> 2;
    int g   = col & 3;
    int row = g * Hdim + jp;
    gxd[idx] = emb[d * 2 + 0] * Wx[row * 2 + 0]
             + emb[d * 2 + 1] * Wx[row * 2 + 1]
             + b[row];
}

__global__ __launch_bounds__(256) void zero_state(float4* __restrict__ p, int n4) {
    int i = blockIdx.x * 256 + threadIdx.x;
    if (i < n4) p[i] = make_float4(0.f, 0.f, 0.f, 0.f);
}

// ---- persistent LSTM: all 128 timesteps in one launch ----
// 256 blocks x 512 thr. mt = blockIdx&31 (32 batch rows), nt = blockIdx>>5
// (64-jp slice). 32 independent chains of 8 blocks; 8-block atomic barrier.
// Wave w holds n-cols [w*32, w*32+32) of the block's 256 gate-interleaved cols
// register-resident (128 VGPRs). c-state register-resident (4 floats/thread).
__global__ __launch_bounds__(512, 2) void lstm_persist(
    const uint4* __restrict__ W6, const float* __restrict__ gxd,
    const int* __restrict__ x, uint4* __restrict__ h0, uint4* __restrict__ h1,
    int* __restrict__ cnt, const float* __restrict__ Wp,
    const float* __restrict__ bp, float* __restrict__ out)
{
    __shared__ uint4 h_s[2048];       // 32 KB  A-tile fragments
    __shared__ float z_s[32 * 260];   // 33 KB  z regroup (padded stride)
    __shared__ int   x_s[4096];       // 16 KB  x transposed [t][b_local]

    const int tid  = threadIdx.x;
    const int w    = tid >> 6;
    const int lane = tid & 63;
    const int mt   = blockIdx.x & 31;
    const int nt   = blockIdx.x >> 5;

    // B-resident W fragments: wave-n-tile wn = nt*8 + w
    s8v bres[32];
    {
        const uint4* wq = W6 + (size_t)(nt * 8 + w) * 2048 + lane;
#pragma unroll
        for (int ks = 0; ks < 32; ks++) bres[ks] = u2s(wq[ks * 64]);
    }
    // x cache, transposed so per-step reads are conflict-free
    for (int i = tid; i < 4096; i += 512) {
        int bl = i & 31, tt = i >> 5;
        x_s[tt * 32 + bl] = x[(mt * 32 + bl) * Tlen + tt];
    }
    __syncthreads();

    const int bl = tid & 31, jg = tid >> 5;
    float c0 = 0.f, c1 = 0.f, c2 = 0.f, c3 = 0.f;
    // h-write address (bf16 units) for this thread's (bl, jp0=nt*64+jg*4)
    const int haddr = mt * 16384 + (nt * 4 + (jg >> 2)) * 512
                    + ((jg >> 1) & 1) * 256 + bl * 8 + (jg & 1) * 4;
    int* mycnt = cnt + mt * 32;

#pragma unroll 1
    for (int t = 0; t < Tlen; t++) {
        const uint4* hr = (t & 1) ? h1 : h0;
        uint4*       hw = (t & 1) ? h0 : h1;

        // stage A tile (coalesced, already fragment-linear)
        for (int i = tid; i < 2048; i += 512) h_s[i] = hr[mt * 2048 + i];
        __syncthreads();

        // K loop: B from registers, A from LDS
        f16v acc = {0,0,0,0,0,0,0,0,0,0,0,0,0,0,0,0};
#pragma unroll
        for (int ks = 0; ks < 32; ks++) {
            s8v a = u2s(h_s[ks * 64 + lane]);
            acc = __builtin_amdgcn_mfma_f32_32x32x16_bf16(a, bres[ks], acc, 0, 0, 0);
        }

        // z scatter (C layout: col = lane&31, row = (r&3)+8*(r>>2)+4*(lane>>5))
        {
            int colb = w * 32 + (lane & 31);
            int rb   = 4 * (lane >> 5);
#pragma unroll
            for (int r = 0; r < 16; r++) {
                int row = (r & 3) + 8 * (r >> 2) + rb;
                z_s[row * 260 + colb] = acc[r];
            }
        }
        __syncthreads();

        // epilogue: thread owns (b=mt*32+bl, jp = nt*64+jg*4 .. +3)
        {
            int d = x_s[t * 32 + bl];
            const float* zr = &z_s[bl * 260 + jg * 16];
            const float* gx = &gxd[d * G4 + nt * 256 + jg * 16];
            float cc[4] = {c0, c1, c2, c3};
            unsigned short hh[4];
#pragma unroll
            for (int i = 0; i < 4; i++) {
                float zg = zr[i*4+0] + gx[i*4+0];
                float zi = zr[i*4+1] + gx[i*4+1];
                float zf = zr[i*4+2] + gx[i*4+2];
                float zo = zr[i*4+3] + gx[i*4+3];
                float gv = 1.f - 2.f / (__expf(2.f * zg) + 1.f);
                float iv = 1.f / (1.f + __expf(-zi));
                float fv = 1.f / (1.f + __expf(-zf));
                float ov = 1.f / (1.f + __expf(-zo));
                float cn = gv * iv + cc[i] * fv;
                cc[i] = cn;
                hh[i] = f2bf((1.f - 2.f / (__expf(2.f * cn) + 1.f)) * ov);
            }
            c0 = cc[0]; c1 = cc[1]; c2 = cc[2]; c3 = cc[3];
            ushort4 hv4 = make_ushort4(hh[0], hh[1], hh[2], hh[3]);
            *(ushort4*)((unsigned short*)hw + haddr) = hv4;
        }

        // 8-block group barrier (release h writes, acquire peers')
        __syncthreads();
        if (tid == 0) {
            __threadfence();
            atomicAdd(mycnt, 1);
            const int target = 8 * (t + 1);
            while (__hip_atomic_load(mycnt, __ATOMIC_RELAXED,
                                     __HIP_MEMORY_SCOPE_AGENT) < target)
                __builtin_amdgcn_s_sleep(2);
            __threadfence();
        }
        __syncthreads();
    }

    // ---- head (nt==0 blocks): p = h.Wp + bp, log_softmax for 32 rows ----
    if (nt == 0) {
        float* wp_s = z_s;   // 5120 floats, reuse z region
        for (int i = tid; i < Hdim * NCLS; i += 512) wp_s[i] = Wp[i];
        __syncthreads();
        const uint4* hf = h0;   // t=127 (odd) wrote h0
#pragma unroll
        for (int rr = 0; rr < 4; rr++) {
            int blr = w * 4 + rr;
            int b   = mt * 32 + blr;
            // lane covers k = lane*8 .. +7 : chunk ks = lane>>1
            uint4 hv = hf[mt * 2048 + (lane >> 1) * 64 + (lane & 1) * 32 + blr];
            union { uint4 u; unsigned short s[8]; } hu; hu.u = hv;
            float a[NCLS];
#pragma unroll
            for (int c = 0; c < NCLS; c++) a[c] = 0.f;
#pragma unroll
            for (int j = 0; j < 8; j++) {
                int k = lane * 8 + j;
                float hvv = bf2f(hu.s[j]);
#pragma unroll
                for (int c = 0; c < NCLS; c++) a[c] += hvv * wp_s[k * NCLS + c];
            }
#pragma unroll
            for (int off = 32; off > 0; off >>= 1) {
#pragma unroll
                for (int c = 0; c < NCLS; c++) a[c] += __shfl_down(a[c], off);
            }
            if (lane == 0) {
                float p[NCLS], m = -1e30f;
#pragma unroll
                for (int c = 0; c < NCLS; c++) { p[c] = a[c] + bp[c]; m = fmaxf(m, p[c]); }
                float s = 0.f;
#pragma unroll
                for (int c = 0; c < NCLS; c++) s += __expf(p[c] - m);
                float lse = m + logf(s);
#pragma unroll
                for (int c = 0; c < NCLS; c++) out[b * NCLS + c] = p[c] - lse;
            }
        }
    }
}

extern "C" void kernel_launch(void* const* d_in, const int* in_sizes, int n_in,
                              void* d_out, int out_size, void* d_ws, size_t ws_size,
                              hipStream_t stream) {
    const int*   x   = (const int*)d_in[0];
    const float* emb = (const float*)d_in[1];
    const float* Wx  = (const float*)d_in[2];
    const float* Wh  = (const float*)d_in[3];
    const float* b   = (const float*)d_in[4];
    const float* Wp  = (const float*)d_in[5];
    const float* bp  = (const float*)d_in[6];
    float* out = (float*)d_out;
    char*  ws  = (char*)d_ws;

    unsigned short* W6  = (unsigned short*)(ws + W6_OFF);
    float*          gxd = (float*)(ws + GXD_OFF);
    uint4*          h0  = (uint4*)(ws + H0_OFF);
    uint4*          h1  = (uint4*)(ws + H1_OFF);
    int*            cnt = (int*)(ws + CNT_OFF);

    prep_w6<<<512, 256, 0, stream>>>(Wh, W6);
    prep_gxd<<<(NDIG * G4 + 255) / 256, 256, 0, stream>>>(emb, Wx, b, gxd);
    // zero h0 + h1 + counters (2 MB + 4 KB contiguous)
    {
        int n4 = (2 * 1024 * 1024 + 4096) / 16;
        zero_state<<<(n4 + 255) / 256, 256, 0, stream>>>((float4*)h0, n4);
    }

    void* args[] = { (void*)&W6, (void*)&gxd, (void*)&x, (void*)&h0, (void*)&h1,
                     (void*)&cnt, (void*)&Wp, (void*)&bp, (void*)&out };
    hipLaunchCooperativeKernel((void*)lstm_persist, dim3(256), dim3(512),
                               args, 0, stream);
}

// Round 5
// 861.587 us; speedup vs baseline: 1.9871x; 1.9871x over previous
//
#include <hip/hip_runtime.h>
#include <math.h>

#define Bsz  1024
#define Tlen 128
#define Hdim 512
#define NCLS 10
#define NDIG 3
#define G4   2048   // 4*H

typedef short s8v __attribute__((ext_vector_type(8)));    // 8 bf16 (4 VGPRs)
typedef float f16v __attribute__((ext_vector_type(16)));  // 32x32 mfma acc

// ---- workspace layout (bytes) ----
// W6 : 2 MB  bf16 frag chunks: uint4 idx = (wn*32+ks)*64 + lane, wn=0..63
// gxd: 24 KB fp32 [d][jp*4+g]  (pad to 32 KB)
// h0/h1: 1 MB bf16 each, chunk layout per mt: uint4 idx = mt*2048 + ks*64 + l
//      elem j = h[b = mt*32 + (l&31)][jp = ks*16 + (l>>5)*8 + j]
// cnt: 4 KB (32 counters, stride 32 ints)
#define W6_OFF  0
#define GXD_OFF (2*1024*1024)
#define H0_OFF  (GXD_OFF + 32*1024)
#define H1_OFF  (H0_OFF + 1024*1024)
#define CNT_OFF (H1_OFF + 1024*1024)

static __device__ __forceinline__ unsigned short f2bf(float f) {
    unsigned int u = __float_as_uint(f);
    u = (u + 0x7FFFu + ((u >> 16) & 1u)) >> 16;   // RNE
    return (unsigned short)u;
}
static __device__ __forceinline__ float bf2f(unsigned short s) {
    return __uint_as_float(((unsigned int)s) << 16);
}
static __device__ __forceinline__ s8v u2s(uint4 v) {
    union { uint4 u; s8v s; } x; x.u = v; return x.s;
}

// ---- prep: W6 fragment chunks for register-resident B ----
__global__ __launch_bounds__(256) void prep_w6(const float* __restrict__ Wh,
                                               unsigned short* __restrict__ W6) {
    int idx = blockIdx.x * 256 + threadIdx.x;   // 0..131071
    int l  = idx & 63;
    int c  = idx >> 6;          // wn*32 + ks
    int ks = c & 31, wn = c >> 5;
    int n  = wn * 32 + (l & 31);
    int jp = n >> 2, g = n & 3;
    int row = g * Hdim + jp;
    int kb  = ks * 16 + (l >> 5) * 8;
    const float* src = &Wh[(size_t)row * Hdim + kb];
    unsigned int p0 = f2bf(src[0]) | ((unsigned int)f2bf(src[1]) << 16);
    unsigned int p1 = f2bf(src[2]) | ((unsigned int)f2bf(src[3]) << 16);
    unsigned int p2 = f2bf(src[4]) | ((unsigned int)f2bf(src[5]) << 16);
    unsigned int p3 = f2bf(src[6]) | ((unsigned int)f2bf(src[7]) << 16);
    ((uint4*)W6)[idx] = make_uint4(p0, p1, p2, p3);
}

__global__ __launch_bounds__(256) void prep_gxd(const float* __restrict__ emb,
                                                const float* __restrict__ Wx,
                                                const float* __restrict__ b,
                                                float* __restrict__ gxd) {
    int idx = blockIdx.x * 256 + threadIdx.x;
    if (idx >= NDIG * G4) return;
    int col = idx % G4;
    int d   = idx / G4;
    int jp  = col >> 2;
    int g   = col & 3;
    int row = g * Hdim + jp;
    gxd[idx] = emb[d * 2 + 0] * Wx[row * 2 + 0]
             + emb[d * 2 + 1] * Wx[row * 2 + 1]
             + b[row];
}

__global__ __launch_bounds__(256) void zero_state(float4* __restrict__ p, int n4) {
    int i = blockIdx.x * 256 + threadIdx.x;
    if (i < n4) p[i] = make_float4(0.f, 0.f, 0.f, 0.f);
}

// ---- persistent LSTM: all 128 timesteps in one launch, fence-free ----
// 256 blocks x 512 thr. mt = blockIdx&31, nt = blockIdx>>5. 32 chains of 8
// blocks; h exchanged via L3 (cache-bypassing relaxed agent atomics), chain
// barrier = relaxed agent atomicAdd + poll. NO threadfence (no L2 flush).
__global__ __launch_bounds__(512, 2) void lstm_persist(
    const uint4* __restrict__ W6, const float* __restrict__ gxd,
    const int* __restrict__ x, uint4* __restrict__ h0, uint4* __restrict__ h1,
    int* __restrict__ cnt, const float* __restrict__ Wp,
    const float* __restrict__ bp, float* __restrict__ out)
{
    __shared__ uint4 h_s[2048];       // 32 KB  A-tile fragments
    __shared__ float z_s[32 * 260];   // 33 KB  z regroup (padded stride)
    __shared__ int   x_s[4096];       // 16 KB  x transposed [t][b_local]

    const int tid  = threadIdx.x;
    const int w    = tid >> 6;
    const int lane = tid & 63;
    const int mt   = blockIdx.x & 31;
    const int nt   = blockIdx.x >> 5;

    // B-resident W fragments: wave-n-tile wn = nt*8 + w
    s8v bres[32];
    {
        const uint4* wq = W6 + (size_t)(nt * 8 + w) * 2048 + lane;
#pragma unroll
        for (int ks = 0; ks < 32; ks++) bres[ks] = u2s(wq[ks * 64]);
    }
    // x cache, transposed so per-step reads are conflict-free
    for (int i = tid; i < 4096; i += 512) {
        int bl = i & 31, tt = i >> 5;
        x_s[tt * 32 + bl] = x[(mt * 32 + bl) * Tlen + tt];
    }
    __syncthreads();

    const int bl = tid & 31, jg = tid >> 5;
    float c0 = 0.f, c1 = 0.f, c2 = 0.f, c3 = 0.f;
    // h-write address (bf16 units) for this thread's (bl, jp0=nt*64+jg*4)
    const int haddr = mt * 16384 + (nt * 4 + (jg >> 2)) * 512
                    + ((jg >> 1) & 1) * 256 + bl * 8 + (jg & 1) * 4;
    int* mycnt = cnt + mt * 32;

#pragma unroll 1
    for (int t = 0; t < Tlen; t++) {
        const uint4* hr = (t & 1) ? h1 : h0;
        uint4*       hw = (t & 1) ? h0 : h1;

        // stage A tile via L3 (cache-bypassing 8B atomic loads)
        {
            const unsigned long long* hr8 =
                (const unsigned long long*)(hr + mt * 2048);
            unsigned long long* hs8 = (unsigned long long*)h_s;
#pragma unroll
            for (int u = 0; u < 8; u++) {
                int i = tid + u * 512;
                hs8[i] = __hip_atomic_load(hr8 + i, __ATOMIC_RELAXED,
                                           __HIP_MEMORY_SCOPE_AGENT);
            }
        }
        __syncthreads();

        // K loop: B from registers, A from LDS
        f16v acc = {0,0,0,0,0,0,0,0,0,0,0,0,0,0,0,0};
#pragma unroll
        for (int ks = 0; ks < 32; ks++) {
            s8v a = u2s(h_s[ks * 64 + lane]);
            acc = __builtin_amdgcn_mfma_f32_32x32x16_bf16(a, bres[ks], acc, 0, 0, 0);
        }

        // z scatter (C layout: col = lane&31, row = (r&3)+8*(r>>2)+4*(lane>>5))
        {
            int colb = w * 32 + (lane & 31);
            int rb   = 4 * (lane >> 5);
#pragma unroll
            for (int r = 0; r < 16; r++) {
                int row = (r & 3) + 8 * (r >> 2) + rb;
                z_s[row * 260 + colb] = acc[r];
            }
        }
        __syncthreads();

        // epilogue: thread owns (b=mt*32+bl, jp = nt*64+jg*4 .. +3)
        {
            int d = x_s[t * 32 + bl];
            const float* zr = &z_s[bl * 260 + jg * 16];
            const float* gx = &gxd[d * G4 + nt * 256 + jg * 16];
            float cc[4] = {c0, c1, c2, c3};
            unsigned short hh[4];
#pragma unroll
            for (int i = 0; i < 4; i++) {
                float zg = zr[i*4+0] + gx[i*4+0];
                float zi = zr[i*4+1] + gx[i*4+1];
                float zf = zr[i*4+2] + gx[i*4+2];
                float zo = zr[i*4+3] + gx[i*4+3];
                float gv = 1.f - 2.f / (__expf(2.f * zg) + 1.f);
                float iv = 1.f / (1.f + __expf(-zi));
                float fv = 1.f / (1.f + __expf(-zf));
                float ov = 1.f / (1.f + __expf(-zo));
                float cn = gv * iv + cc[i] * fv;
                cc[i] = cn;
                hh[i] = f2bf((1.f - 2.f / (__expf(2.f * cn) + 1.f)) * ov);
            }
            c0 = cc[0]; c1 = cc[1]; c2 = cc[2]; c3 = cc[3];
            unsigned long long hv8 =
                  (unsigned long long)hh[0]
                | ((unsigned long long)hh[1] << 16)
                | ((unsigned long long)hh[2] << 32)
                | ((unsigned long long)hh[3] << 48);
            __hip_atomic_store((unsigned long long*)((unsigned short*)hw + haddr),
                               hv8, __ATOMIC_RELAXED, __HIP_MEMORY_SCOPE_AGENT);
        }

        // drain own stores to the coherent point, then chain barrier
        asm volatile("s_waitcnt vmcnt(0)" ::: "memory");
        __syncthreads();
        if (tid == 0) {
            __hip_atomic_fetch_add(mycnt, 1, __ATOMIC_RELAXED,
                                   __HIP_MEMORY_SCOPE_AGENT);
            const int target = 8 * (t + 1);
            while (__hip_atomic_load(mycnt, __ATOMIC_RELAXED,
                                     __HIP_MEMORY_SCOPE_AGENT) < target)
                __builtin_amdgcn_s_sleep(1);
        }
        __syncthreads();
    }

    // ---- head (nt==0 blocks): p = h.Wp + bp, log_softmax for 32 rows ----
    if (nt == 0) {
        float* wp_s = z_s;   // 5120 floats, reuse z region
        for (int i = tid; i < Hdim * NCLS; i += 512) wp_s[i] = Wp[i];
        __syncthreads();
        const unsigned long long* hf8 =
            (const unsigned long long*)(h0 + mt * 2048);   // t=127 wrote h0
#pragma unroll
        for (int rr = 0; rr < 4; rr++) {
            int blr = w * 4 + rr;
            int b   = mt * 32 + blr;
            // lane covers k = lane*8 .. +7 : uint4 idx = (lane>>1)*64 + (lane&1)*32 + blr
            int u4 = (lane >> 1) * 64 + (lane & 1) * 32 + blr;
            unsigned long long lo = __hip_atomic_load(hf8 + u4 * 2, __ATOMIC_RELAXED,
                                                      __HIP_MEMORY_SCOPE_AGENT);
            unsigned long long hi = __hip_atomic_load(hf8 + u4 * 2 + 1, __ATOMIC_RELAXED,
                                                      __HIP_MEMORY_SCOPE_AGENT);
            union { unsigned long long q[2]; unsigned short s[8]; } hu;
            hu.q[0] = lo; hu.q[1] = hi;
            float a[NCLS];
#pragma unroll
            for (int c = 0; c < NCLS; c++) a[c] = 0.f;
#pragma unroll
            for (int j = 0; j < 8; j++) {
                int k = lane * 8 + j;
                float hvv = bf2f(hu.s[j]);
#pragma unroll
                for (int c = 0; c < NCLS; c++) a[c] += hvv * wp_s[k * NCLS + c];
            }
#pragma unroll
            for (int off = 32; off > 0; off >>= 1) {
#pragma unroll
                for (int c = 0; c < NCLS; c++) a[c] += __shfl_down(a[c], off);
            }
            if (lane == 0) {
                float p[NCLS], m = -1e30f;
#pragma unroll
                for (int c = 0; c < NCLS; c++) { p[c] = a[c] + bp[c]; m = fmaxf(m, p[c]); }
                float s = 0.f;
#pragma unroll
                for (int c = 0; c < NCLS; c++) s += __expf(p[c] - m);
                float lse = m + logf(s);
#pragma unroll
                for (int c = 0; c < NCLS; c++) out[b * NCLS + c] = p[c] - lse;
            }
        }
    }
}

extern "C" void kernel_launch(void* const* d_in, const int* in_sizes, int n_in,
                              void* d_out, int out_size, void* d_ws, size_t ws_size,
                              hipStream_t stream) {
    const int*   x   = (const int*)d_in[0];
    const float* emb = (const float*)d_in[1];
    const float* Wx  = (const float*)d_in[2];
    const float* Wh  = (const float*)d_in[3];
    const float* b   = (const float*)d_in[4];
    const float* Wp  = (const float*)d_in[5];
    const float* bp  = (const float*)d_in[6];
    float* out = (float*)d_out;
    char*  ws  = (char*)d_ws;

    unsigned short* W6  = (unsigned short*)(ws + W6_OFF);
    float*          gxd = (float*)(ws + GXD_OFF);
    uint4*          h0  = (uint4*)(ws + H0_OFF);
    uint4*          h1  = (uint4*)(ws + H1_OFF);
    int*            cnt = (int*)(ws + CNT_OFF);

    prep_w6<<<512, 256, 0, stream>>>(Wh, W6);
    prep_gxd<<<(NDIG * G4 + 255) / 256, 256, 0, stream>>>(emb, Wx, b, gxd);
    // zero h0 + h1 + counters (2 MB + 4 KB contiguous)
    {
        int n4 = (2 * 1024 * 1024 + 4096) / 16;
        zero_state<<<(n4 + 255) / 256, 256, 0, stream>>>((float4*)h0, n4);
    }

    void* args[] = { (void*)&W6, (void*)&gxd, (void*)&x, (void*)&h0, (void*)&h1,
                     (void*)&cnt, (void*)&Wp, (void*)&bp, (void*)&out };
    hipLaunchCooperativeKernel((void*)lstm_persist, dim3(256), dim3(512),
                               args, 0, stream);
}